// Round 3
// baseline (4308.384 us; speedup 1.0000x reference)
//
#include <hip/hip_runtime.h>
#include <cstdint>
#include <cstddef>

#define Vv 32000
#define Ee 512
#define Hh 512
#define Bb 32
#define Ss 128

typedef __bf16 bf16x8 __attribute__((ext_vector_type(8)));
typedef float  f32x4  __attribute__((ext_vector_type(4)));

__device__ __forceinline__ float b2f(unsigned short u) {
  union { unsigned int i; float f; } v; v.i = ((unsigned int)u) << 16; return v.f;
}
__device__ __forceinline__ unsigned short f2b(float f) {
  union { float f; unsigned int i; } v; v.f = f;
  unsigned int r = v.i + 0x7FFFu + ((v.i >> 16) & 1u);
  return (unsigned short)(r >> 16);
}
__device__ __forceinline__ float sigm(float x) { return 1.f / (1.f + __expf(-x)); }

// Cross-XCD coherent state access: relaxed agent-scope atomics bypass the
// non-coherent per-XCD L2 (sc1) -> no cache-wide invalidates needed anywhere.
__device__ __forceinline__ bf16x8 aload16(const unsigned short* p) {
  unsigned long long lo = __hip_atomic_load((const unsigned long long*)p,
                                            __ATOMIC_RELAXED, __HIP_MEMORY_SCOPE_AGENT);
  unsigned long long hi = __hip_atomic_load((const unsigned long long*)(p + 4),
                                            __ATOMIC_RELAXED, __HIP_MEMORY_SCOPE_AGENT);
  union { unsigned long long u[2]; bf16x8 v; } r;
  r.u[0] = lo; r.u[1] = hi;
  return r.v;
}
__device__ __forceinline__ void astore8(unsigned short* p, unsigned long long v) {
  __hip_atomic_store((unsigned long long*)p, v, __ATOMIC_RELAXED, __HIP_MEMORY_SCOPE_AGENT);
}

// ---------------- prep kernels ----------------

__global__ void zero_flags(unsigned* p) { if (threadIdx.x < 64) p[threadIdx.x] = 0u; }

__global__ void cast_bf16(const float* __restrict__ src, unsigned short* __restrict__ dst, int n4) {
  int i = blockIdx.x * 256 + threadIdx.x;
  if (i >= n4) return;
  float4 v = reinterpret_cast<const float4*>(src)[i];
  ushort4 o;
  o.x = f2b(v.x); o.y = f2b(v.y); o.z = f2b(v.z); o.w = f2b(v.w);
  reinterpret_cast<ushort4*>(dst)[i] = o;
}

// w1cat[d][n][0..1023] = w_ih1[d][n][*]; [1024..1535] = w_hh1[d][n][*]
__global__ void pack_w1(const float* __restrict__ ih, const float* __restrict__ hh,
                        unsigned short* __restrict__ dst) {
  int r = blockIdx.x;  // d*1536 + n
  const float* si = ih + (size_t)r * 1024;
  const float* sh = hh + (size_t)r * 512;
  unsigned short* dr = dst + (size_t)r * 1536;
  for (int c = threadIdx.x; c < 1024; c += 256) dr[c] = f2b(si[c]);
  for (int c = threadIdx.x; c < 512; c += 256) dr[1024 + c] = f2b(sh[c]);
}

// emb_bf16[s][b][e]
__global__ void embed_gather(const int* __restrict__ target, const float* __restrict__ table,
                             unsigned short* __restrict__ emb) {
  int sb = blockIdx.x;           // s*32 + b
  int s = sb >> 5, b = sb & 31;
  int tok = target[b * Ss + s];
  float4 v = reinterpret_cast<const float4*>(table + (size_t)tok * Ee)[threadIdx.x];
  ushort4 o;
  o.x = f2b(v.x); o.y = f2b(v.y); o.z = f2b(v.z); o.w = f2b(v.w);
  reinterpret_cast<ushort4*>(emb + (size_t)sb * Ee)[threadIdx.x] = o;
}

// ---------------- bf16 MFMA GEMM: C = A * B^T + bias ----------------
// MODE 0: C bf16 [M][ldc], row = A-row; z via sBz/sCz/sBiasz (grid.z)
// MODE 1: C f32, row remap r=(s*32+b) -> out row (b*128+s), ldc=Vv,
//         nontemporal C stores + per-(row,colblock) partial max/sumexp output.
template <int MODE>
__global__ __launch_bounds__(256, 2) void gemm_nt(
    const unsigned short* __restrict__ A, const unsigned short* __restrict__ Bm,
    const float* __restrict__ bias, void* __restrict__ Cout,
    int K, int ldc, size_t sBz, size_t sCz, size_t sBiasz,
    float* __restrict__ pm, float* __restrict__ ps) {
  int z = blockIdx.z;
  Bm += z * sBz;
  bias += z * sBiasz;

  __shared__ __align__(16) unsigned short As[128 * 64];
  __shared__ __align__(16) unsigned short Bs[128 * 64];
  __shared__ float smx[128][2], sse[128][2];

  int t = threadIdx.x;
  int m0 = blockIdx.x * 128, n0 = blockIdx.y * 128;
  int wave = t >> 6, lane = t & 63;
  int wr = wave >> 1, wc = wave & 1;

  f32x4 acc[4][4] = {};

  int kt = K >> 6;
  for (int ks = 0; ks < kt; ++ks) {
    int k0 = ks << 6;
#pragma unroll
    for (int c = 0; c < 4; ++c) {
      int v = c * 256 + t;
      int row = v >> 3, col = (v & 7) * 8;
      uint4 da = *reinterpret_cast<const uint4*>(A + (size_t)(m0 + row) * K + k0 + col);
      uint4 db = *reinterpret_cast<const uint4*>(Bm + (size_t)(n0 + row) * K + k0 + col);
      *reinterpret_cast<uint4*>(As + v * 8) = da;
      *reinterpret_cast<uint4*>(Bs + v * 8) = db;
    }
    __syncthreads();
#pragma unroll
    for (int kk = 0; kk < 2; ++kk) {
      bf16x8 af[4], bfr[4];
      int lrow = lane & 15, lk = kk * 32 + (lane >> 4) * 8;
#pragma unroll
      for (int m = 0; m < 4; ++m)
        af[m] = *reinterpret_cast<const bf16x8*>(As + (wr * 64 + m * 16 + lrow) * 64 + lk);
#pragma unroll
      for (int n = 0; n < 4; ++n)
        bfr[n] = *reinterpret_cast<const bf16x8*>(Bs + (wc * 64 + n * 16 + lrow) * 64 + lk);
#pragma unroll
      for (int m = 0; m < 4; ++m)
#pragma unroll
        for (int n = 0; n < 4; ++n)
          acc[m][n] = __builtin_amdgcn_mfma_f32_16x16x32_bf16(af[m], bfr[n], acc[m][n], 0, 0, 0);
    }
    __syncthreads();
  }

  int lrow4 = (lane >> 4) * 4, lcol = lane & 15;
  if (MODE == 0) {
#pragma unroll
    for (int m = 0; m < 4; ++m) {
      int rbase = m0 + wr * 64 + m * 16 + lrow4;
#pragma unroll
      for (int n = 0; n < 4; ++n) {
        int col = n0 + wc * 64 + n * 16 + lcol;
        float bv = bias[col];
#pragma unroll
        for (int j = 0; j < 4; ++j) {
          int r = rbase + j;
          float vv = acc[m][n][j] + bv;
          ((unsigned short*)Cout)[z * sCz + (size_t)r * ldc + col] = f2b(vv);
        }
      }
    }
  } else {
    float bv[4];
#pragma unroll
    for (int n = 0; n < 4; ++n) bv[n] = bias[n0 + wc * 64 + n * 16 + lcol];
#pragma unroll
    for (int m = 0; m < 4; ++m) {
#pragma unroll
      for (int j = 0; j < 4; ++j) {
        float x[4];
#pragma unroll
        for (int n = 0; n < 4; ++n) x[n] = acc[m][n][j] + bv[n];
        int rib = wr * 64 + m * 16 + lrow4 + j;
        int r = m0 + rib;
        int b = r & 31, s = r >> 5;
        float* crow = (float*)Cout + (size_t)(b * Ss + s) * ldc;
#pragma unroll
        for (int n = 0; n < 4; ++n)
          __builtin_nontemporal_store(x[n], crow + n0 + wc * 64 + n * 16 + lcol);
        float mx = fmaxf(fmaxf(x[0], x[1]), fmaxf(x[2], x[3]));
#pragma unroll
        for (int msk = 1; msk < 16; msk <<= 1) mx = fmaxf(mx, __shfl_xor(mx, msk, 16));
        float se = __expf(x[0] - mx) + __expf(x[1] - mx) + __expf(x[2] - mx) + __expf(x[3] - mx);
#pragma unroll
        for (int msk = 1; msk < 16; msk <<= 1) se += __shfl_xor(se, msk, 16);
        if (lcol == 0) { smx[rib][wc] = mx; sse[rib][wc] = se; }
      }
    }
    __syncthreads();
    if (t < 128) {
      float ma = smx[t][0], mb = smx[t][1];
      float M = fmaxf(ma, mb);
      float S = sse[t][0] * __expf(ma - M) + sse[t][1] * __expf(mb - M);
      int rg = m0 + t;
      int b = rg & 31, s = rg >> 5;
      size_t orow = (size_t)(b * Ss + s);
      pm[orow * 250 + blockIdx.y] = M;
      ps[orow * 250 + blockIdx.y] = S;
    }
  }
}

// ---------------- persistent recurrence kernel ----------------
// grid = 128 blocks x 384 threads. blk<64: layer1; blk>=64: layer0.
// State exchange (XH, H0) via relaxed agent atomics (L2-bypass, coherent).
// Weights/gi0 via normal loads -> stay L2-resident (no invalidates issued).

#define MFMA16 __builtin_amdgcn_mfma_f32_16x16x32_bf16

__device__ __forceinline__ void chain2a(const unsigned short* __restrict__ a0,
                                        const unsigned short* __restrict__ a1,
                                        const unsigned short* __restrict__ b, int n,
                                        f32x4& c0, f32x4& c1) {
#pragma unroll 4
  for (int i = 0; i < n; ++i) {
    bf16x8 bv = *reinterpret_cast<const bf16x8*>(b + i * 32);
    bf16x8 av0 = aload16(a0 + i * 32);
    bf16x8 av1 = aload16(a1 + i * 32);
    c0 = MFMA16(av0, bv, c0, 0, 0, 0);
    c1 = MFMA16(av1, bv, c1, 0, 0, 0);
  }
}

__global__ __launch_bounds__(384, 1) void pers_kernel(
    const unsigned short* __restrict__ gi0,
    const unsigned short* __restrict__ whh0b, const unsigned short* __restrict__ w1cat,
    const float* __restrict__ b_hh0, const float* __restrict__ b_ih1, const float* __restrict__ b_hh1,
    const float* __restrict__ context,
    unsigned short* __restrict__ XH, unsigned short* __restrict__ H0,
    unsigned short* __restrict__ outs, unsigned* bar) {
  __shared__ float pre[7][16][33];
  __shared__ float hf[32][16];
  __shared__ float bA[16], bB[16], bC[16], bD[16];
  __shared__ unsigned sAbort;

  const int tid = threadIdx.x, blk = blockIdx.x;
  const int w = tid >> 6, lane = tid & 63, ln = lane & 15;
  const int hi8 = (lane >> 4) * 8;
  const bool isL1 = blk < 64;
  const int d = (blk & 63) >> 5, j0 = (blk & 31) * 16;
  const int g = w >> 1, kh = w & 1;

  // barrier: release add (writeback only), relaxed spin (NO acquire -> no L2 inv)
  auto gbar = [&](unsigned expected) -> bool {
    __syncthreads();
    if (tid == 0) {
      __hip_atomic_fetch_add(bar, 1u, __ATOMIC_RELEASE, __HIP_MEMORY_SCOPE_AGENT);
      unsigned long long t0 = __builtin_amdgcn_s_memrealtime();
      while (__hip_atomic_load(bar, __ATOMIC_RELAXED, __HIP_MEMORY_SCOPE_AGENT) < expected) {
        if (__hip_atomic_load(bar + 1, __ATOMIC_RELAXED, __HIP_MEMORY_SCOPE_AGENT) != 0u ||
            (__builtin_amdgcn_s_memrealtime() - t0) > 100000000ULL) {
          __hip_atomic_store(bar + 1, 1u, __ATOMIC_RELAXED, __HIP_MEMORY_SCOPE_AGENT);
          break;
        }
      }
      sAbort = __hip_atomic_load(bar + 1, __ATOMIC_RELAXED, __HIP_MEMORY_SCOPE_AGENT);
    }
    __syncthreads();
    return sAbort != 0u;
  };

  auto stile = [&](int s, f32x4 v0, f32x4 v1) {
    int c = ln, r0 = (lane >> 4) * 4;
#pragma unroll
    for (int j = 0; j < 4; ++j) {
      pre[s][c][r0 + j] = v0[j];
      pre[s][c][16 + r0 + j] = v1[j];
    }
  };

  // ---- init: biases + h state ----
  if (tid < 16) {
    int jj = tid;
    if (isL1) {
      bA[jj] = b_ih1[d * 1536 + j0 + jj] + b_hh1[d * 1536 + j0 + jj];
      bB[jj] = b_ih1[d * 1536 + 512 + j0 + jj] + b_hh1[d * 1536 + 512 + j0 + jj];
      bC[jj] = b_ih1[d * 1536 + 1024 + j0 + jj];
      bD[jj] = b_hh1[d * 1536 + 1024 + j0 + jj];
    } else {
      bA[jj] = b_hh0[d * 1536 + j0 + jj];
      bB[jj] = b_hh0[d * 1536 + 512 + j0 + jj];
      bC[jj] = b_hh0[d * 1536 + 1024 + j0 + jj];
    }
  }
  {
    int layer = isL1 ? 1 : 0;
    for (int i = tid; i < 128; i += 384) {
      int b = i >> 2, j4 = (i & 3) * 4;
      unsigned long long pk = 0;
#pragma unroll
      for (int k = 0; k < 4; ++k) {
        float c = context[(((size_t)layer * 2 + d) * 32 + b) * 512 + j0 + j4 + k];
        hf[b][j4 + k] = c;
        pk |= ((unsigned long long)f2b(c)) << (16 * k);
      }
      if (isL1) astore8(XH + (size_t)b * 2048 + 1024 + d * 512 + j0 + j4, pk);       // parity 0
      else      astore8(H0 + (size_t)32768 + ((size_t)d * 32 + b) * 512 + j0 + j4, pk); // parity 1
    }
  }
  if (gbar(128u)) return;

  // ---- phase loop ----
  for (int p = 0; p <= 128; ++p) {
    if (isL1) {
      if (p >= 1) {
        int par = (p - 1) & 1;
        const unsigned short* Bw =
            w1cat + ((size_t)d * 1536 + g * 512 + j0 + ln) * 1536 + kh * 768 + hi8;
        const unsigned short* Ar = XH + (size_t)par * 65536 + (size_t)ln * 2048;
        f32x4 p0 = {}, p1 = {}, q0 = {}, q1 = {};
        int cb = kh * 768 + hi8;
        if (kh == 0) {
          chain2a(Ar + cb, Ar + 16 * 2048 + cb, Bw, 24, p0, p1);
        } else {
          chain2a(Ar + cb, Ar + 16 * 2048 + cb, Bw, 8, p0, p1);
          int c2 = 1024 + d * 512 + hi8;
          if (g == 2) chain2a(Ar + c2, Ar + 16 * 2048 + c2, Bw + 256, 16, q0, q1);
          else        chain2a(Ar + c2, Ar + 16 * 2048 + c2, Bw + 256, 16, p0, p1);
        }
        int slot = (g < 2) ? g * 2 + kh : (kh == 0 ? 4 : 5);
        stile(slot, p0, p1);
        if (g == 2 && kh == 1) stile(6, q0, q1);
      }
    } else {
      if (p <= 127) {
        int par2 = (p + 1) & 1;
        const unsigned short* Bw =
            whh0b + ((size_t)d * 1536 + g * 512 + j0 + ln) * 512 + kh * 256 + hi8;
        const unsigned short* Ar =
            H0 + (size_t)par2 * 32768 + ((size_t)d * 32 + ln) * 512 + kh * 256 + hi8;
        f32x4 p0 = {}, p1 = {};
        chain2a(Ar, Ar + 16 * 512, Bw, 8, p0, p1);
        int slot = (g < 2) ? g * 2 + kh : 4 + kh;
        stile(slot, p0, p1);
      }
    }
    __syncthreads();
    if (isL1) {
      if (p >= 1) {
        int t_ = p - 1;
        for (int i = tid; i < 128; i += 384) {
          int b = i >> 2, j4 = (i & 3) * 4;
          unsigned long long pk = 0;
#pragma unroll
          for (int k = 0; k < 4; ++k) {
            int jj = j4 + k;
            float r = sigm(pre[0][jj][b] + pre[1][jj][b] + bA[jj]);
            float z = sigm(pre[2][jj][b] + pre[3][jj][b] + bB[jj]);
            float nn = tanhf(pre[4][jj][b] + pre[5][jj][b] + bC[jj] +
                             r * (pre[6][jj][b] + bD[jj]));
            float h = hf[b][jj];
            float hnew = (1.f - z) * nn + z * h;
            hf[b][jj] = hnew;
            pk |= ((unsigned long long)f2b(hnew)) << (16 * k);
          }
          astore8(XH + (size_t)(p & 1) * 65536 + (size_t)b * 2048 + 1024 + d * 512 + j0 + j4, pk);
          __builtin_nontemporal_store(
              pk, (unsigned long long*)(outs + ((size_t)t_ * 32 + b) * 1024 + (size_t)d * 512 + j0 + j4));
        }
      }
    } else {
      if (p <= 127) {
        const unsigned short* gz = gi0 + ((size_t)d * 128 + p) * 32 * 1536;
        for (int i = tid; i < 128; i += 384) {
          int b = i >> 2, j4 = (i & 3) * 4;
          int col = j0 + j4;
          unsigned long long gr = *(const unsigned long long*)(gz + b * 1536 + col);
          unsigned long long gzt = *(const unsigned long long*)(gz + b * 1536 + 512 + col);
          unsigned long long gn = *(const unsigned long long*)(gz + b * 1536 + 1024 + col);
          unsigned long long pk = 0;
#pragma unroll
          for (int k = 0; k < 4; ++k) {
            int jj = j4 + k;
            float gir = b2f((unsigned short)(gr >> (16 * k)));
            float giz = b2f((unsigned short)(gzt >> (16 * k)));
            float gin = b2f((unsigned short)(gn >> (16 * k)));
            float r = sigm(gir + pre[0][jj][b] + pre[1][jj][b] + bA[jj]);
            float z = sigm(giz + pre[2][jj][b] + pre[3][jj][b] + bB[jj]);
            float nn = tanhf(gin + r * (pre[4][jj][b] + pre[5][jj][b] + bC[jj]));
            float h = hf[b][jj];
            float hnew = (1.f - z) * nn + z * h;
            hf[b][jj] = hnew;
            pk |= ((unsigned long long)f2b(hnew)) << (16 * k);
          }
          astore8(H0 + (size_t)(p & 1) * 32768 + ((size_t)d * 32 + b) * 512 + col, pk);
          astore8(XH + (size_t)(p & 1) * 65536 + (size_t)b * 2048 + d * 512 + col, pk);
        }
      }
    }
    if (gbar(128u * (unsigned)(p + 2))) return;
  }
}

// ---------------- log-softmax: partial reduce + subtract ----------------

__global__ __launch_bounds__(128) void lse_reduce(const float* __restrict__ pm,
                                                  const float* __restrict__ ps,
                                                  float* __restrict__ lsebuf) {
  int r = blockIdx.x * 128 + threadIdx.x;
  const float* pmr = pm + (size_t)r * 250;
  const float* psr = ps + (size_t)r * 250;
  float M = -1e30f, S = 0.f;
  for (int i = 0; i < 250; ++i) {
    float m2 = pmr[i], s2 = psr[i];
    if (m2 <= M) {
      S += s2 * __expf(m2 - M);
    } else {
      S = S * __expf(M - m2) + s2;
      M = m2;
    }
  }
  lsebuf[r] = M + __logf(S);
}

__global__ __launch_bounds__(256) void sub_lse(float* __restrict__ out,
                                               const float* __restrict__ lsebuf) {
  int row = blockIdx.x;
  float l = lsebuf[row];
  f32x4* rp = (f32x4*)(out + (size_t)row * Vv);
  for (int i = threadIdx.x; i < 8000; i += 256) {
    f32x4 v = __builtin_nontemporal_load(rp + i);
    v[0] -= l; v[1] -= l; v[2] -= l; v[3] -= l;
    __builtin_nontemporal_store(v, rp + i);
  }
}

// ---------------- host ----------------

extern "C" void kernel_launch(void* const* d_in, const int* in_sizes, int n_in,
                              void* d_out, int out_size, void* d_ws, size_t ws_size,
                              hipStream_t stream) {
  (void)in_sizes; (void)n_in; (void)out_size; (void)ws_size;
  const int*   target  = (const int*)  d_in[0];
  const float* context = (const float*)d_in[2];
  const float* table   = (const float*)d_in[3];
  const float* w_ih0   = (const float*)d_in[4];
  const float* w_hh0   = (const float*)d_in[5];
  const float* b_ih0   = (const float*)d_in[6];
  const float* b_hh0   = (const float*)d_in[7];
  const float* w_ih1   = (const float*)d_in[8];
  const float* w_hh1   = (const float*)d_in[9];
  const float* b_ih1   = (const float*)d_in[10];
  const float* b_hh1   = (const float*)d_in[11];
  const float* fc_w    = (const float*)d_in[12];
  const float* fc_b    = (const float*)d_in[13];
  float* out = (float*)d_out;

  uint8_t* ws = (uint8_t*)d_ws;
  size_t off = 0;
  auto alloc = [&](size_t bytes) {
    uint8_t* p = ws + off;
    off += (bytes + 255) & ~(size_t)255;
    return p;
  };
  unsigned*       bar   = (unsigned*)alloc(256);
  unsigned short* XH    = (unsigned short*)alloc((size_t)2 * 32 * 2048 * 2);
  unsigned short* H0    = (unsigned short*)alloc((size_t)2 * 2 * 32 * 512 * 2);
  unsigned short* whh0b = (unsigned short*)alloc((size_t)1572864 * 2);
  unsigned short* w1cat = (unsigned short*)alloc((size_t)2 * 1536 * 1536 * 2);
  unsigned short* embb  = (unsigned short*)alloc((size_t)2097152 * 2);
  unsigned short* wih0b = (unsigned short*)alloc((size_t)1572864 * 2);
  unsigned short* gi0   = (unsigned short*)alloc((size_t)12582912 * 2);
  unsigned short* outsb = (unsigned short*)alloc((size_t)4194304 * 2);
  unsigned short* fcwb  = (unsigned short*)alloc((size_t)32768000 * 2);

  // partials + lse overlay gi0's region (gi0 is dead once pers_kernel finishes)
  float* pm     = (float*)gi0;
  float* ps     = pm + (size_t)4096 * 250;
  float* lsebuf = ps + (size_t)4096 * 250;

  // prep
  zero_flags<<<dim3(1), 64, 0, stream>>>(bar);
  cast_bf16<<<dim3(1536), 256, 0, stream>>>(w_ih0, wih0b, 393216);
  cast_bf16<<<dim3(1536), 256, 0, stream>>>(w_hh0, whh0b, 393216);
  cast_bf16<<<dim3(32000), 256, 0, stream>>>(fc_w, fcwb, 8192000);
  pack_w1<<<dim3(3072), 256, 0, stream>>>(w_ih1, w_hh1, w1cat);
  embed_gather<<<dim3(4096), 128, 0, stream>>>(target, table, embb);

  // gi0 = emb * w_ih0^T + b_ih0  (bf16 out [d][4096][1536])
  gemm_nt<0><<<dim3(32, 12, 2), 256, 0, stream>>>(
      embb, wih0b, b_ih0, gi0, 512, 1536,
      (size_t)1536 * 512, (size_t)4096 * 1536, (size_t)1536, nullptr, nullptr);

  // recurrence: one persistent kernel, 130 relaxed grid barriers
  pers_kernel<<<dim3(128), 384, 0, stream>>>(
      gi0, whh0b, w1cat, b_hh0, b_ih1, b_hh1, context, XH, H0, outsb, bar);

  // logits = outs * fc_w^T + fc_b  (row remap (s,b)->(b,s)) + LSE partials
  gemm_nt<1><<<dim3(32, 250, 1), 256, 0, stream>>>(
      outsb, fcwb, fc_b, out, 1024, Vv, 0, 0, 0, pm, ps);

  // log_softmax: reduce partials then subtract
  lse_reduce<<<dim3(32), 128, 0, stream>>>(pm, ps, lsebuf);
  sub_lse<<<dim3(4096), 256, 0, stream>>>(out, lsebuf);
}

// Round 4
// 1376.626 us; speedup vs baseline: 3.1297x; 3.1297x over previous
//
#include <hip/hip_runtime.h>
#include <cstdint>
#include <cstddef>

#define Vv 32000
#define Ee 512
#define Hh 512
#define Bb 32
#define Ss 128

typedef __bf16 bf16x8 __attribute__((ext_vector_type(8)));
typedef float  f32x4  __attribute__((ext_vector_type(4)));
typedef unsigned long long ull;

__device__ __forceinline__ float b2f(unsigned short u) {
  union { unsigned int i; float f; } v; v.i = ((unsigned int)u) << 16; return v.f;
}
__device__ __forceinline__ unsigned short f2b(float f) {
  union { float f; unsigned int i; } v; v.f = f;
  unsigned int r = v.i + 0x7FFFu + ((v.i >> 16) & 1u);
  return (unsigned short)(r >> 16);
}
__device__ __forceinline__ float sigm(float x) { return 1.f / (1.f + __expf(-x)); }

// Cross-XCD coherent 8B ops (sc1 path through the coherence point).
__device__ __forceinline__ ull aload8(const unsigned short* p) {
  return __hip_atomic_load((const ull*)p, __ATOMIC_RELAXED, __HIP_MEMORY_SCOPE_AGENT);
}
__device__ __forceinline__ void astore8(unsigned short* p, ull v) {
  __hip_atomic_store((ull*)p, v, __ATOMIC_RELAXED, __HIP_MEMORY_SCOPE_AGENT);
}

// ---------------- prep kernels ----------------

__global__ void zero_flags(unsigned* p) {
  for (int i = threadIdx.x; i < 1024; i += 256) p[i] = 0u;
}

__global__ void cast_bf16(const float* __restrict__ src, unsigned short* __restrict__ dst, int n4) {
  int i = blockIdx.x * 256 + threadIdx.x;
  if (i >= n4) return;
  float4 v = reinterpret_cast<const float4*>(src)[i];
  ushort4 o;
  o.x = f2b(v.x); o.y = f2b(v.y); o.z = f2b(v.z); o.w = f2b(v.w);
  reinterpret_cast<ushort4*>(dst)[i] = o;
}

// w1cat[d][n][0..1023] = w_ih1[d][n][*]; [1024..1535] = w_hh1[d][n][*]
__global__ void pack_w1(const float* __restrict__ ih, const float* __restrict__ hh,
                        unsigned short* __restrict__ dst) {
  int r = blockIdx.x;  // d*1536 + n
  const float* si = ih + (size_t)r * 1024;
  const float* sh = hh + (size_t)r * 512;
  unsigned short* dr = dst + (size_t)r * 1536;
  for (int c = threadIdx.x; c < 1024; c += 256) dr[c] = f2b(si[c]);
  for (int c = threadIdx.x; c < 512; c += 256) dr[1024 + c] = f2b(sh[c]);
}

// emb_bf16[s][b][e]
__global__ void embed_gather(const int* __restrict__ target, const float* __restrict__ table,
                             unsigned short* __restrict__ emb) {
  int sb = blockIdx.x;           // s*32 + b
  int s = sb >> 5, b = sb & 31;
  int tok = target[b * Ss + s];
  float4 v = reinterpret_cast<const float4*>(table + (size_t)tok * Ee)[threadIdx.x];
  ushort4 o;
  o.x = f2b(v.x); o.y = f2b(v.y); o.z = f2b(v.z); o.w = f2b(v.w);
  reinterpret_cast<ushort4*>(emb + (size_t)sb * Ee)[threadIdx.x] = o;
}

// ---------------- bf16 MFMA GEMM: C = A * B^T + bias ----------------
template <int MODE>
__global__ __launch_bounds__(256, 2) void gemm_nt(
    const unsigned short* __restrict__ A, const unsigned short* __restrict__ Bm,
    const float* __restrict__ bias, void* __restrict__ Cout,
    int K, int ldc, size_t sBz, size_t sCz, size_t sBiasz,
    float* __restrict__ pm, float* __restrict__ ps) {
  int z = blockIdx.z;
  Bm += z * sBz;
  bias += z * sBiasz;

  __shared__ __align__(16) unsigned short As[128 * 64];
  __shared__ __align__(16) unsigned short Bs[128 * 64];
  __shared__ float smx[128][2], sse[128][2];

  int t = threadIdx.x;
  int m0 = blockIdx.x * 128, n0 = blockIdx.y * 128;
  int wave = t >> 6, lane = t & 63;
  int wr = wave >> 1, wc = wave & 1;

  f32x4 acc[4][4] = {};

  int kt = K >> 6;
  for (int ks = 0; ks < kt; ++ks) {
    int k0 = ks << 6;
#pragma unroll
    for (int c = 0; c < 4; ++c) {
      int v = c * 256 + t;
      int row = v >> 3, col = (v & 7) * 8;
      uint4 da = *reinterpret_cast<const uint4*>(A + (size_t)(m0 + row) * K + k0 + col);
      uint4 db = *reinterpret_cast<const uint4*>(Bm + (size_t)(n0 + row) * K + k0 + col);
      *reinterpret_cast<uint4*>(As + v * 8) = da;
      *reinterpret_cast<uint4*>(Bs + v * 8) = db;
    }
    __syncthreads();
#pragma unroll
    for (int kk = 0; kk < 2; ++kk) {
      bf16x8 af[4], bfr[4];
      int lrow = lane & 15, lk = kk * 32 + (lane >> 4) * 8;
#pragma unroll
      for (int m = 0; m < 4; ++m)
        af[m] = *reinterpret_cast<const bf16x8*>(As + (wr * 64 + m * 16 + lrow) * 64 + lk);
#pragma unroll
      for (int n = 0; n < 4; ++n)
        bfr[n] = *reinterpret_cast<const bf16x8*>(Bs + (wc * 64 + n * 16 + lrow) * 64 + lk);
#pragma unroll
      for (int m = 0; m < 4; ++m)
#pragma unroll
        for (int n = 0; n < 4; ++n)
          acc[m][n] = __builtin_amdgcn_mfma_f32_16x16x32_bf16(af[m], bfr[n], acc[m][n], 0, 0, 0);
    }
    __syncthreads();
  }

  int lrow4 = (lane >> 4) * 4, lcol = lane & 15;
  if (MODE == 0) {
#pragma unroll
    for (int m = 0; m < 4; ++m) {
      int rbase = m0 + wr * 64 + m * 16 + lrow4;
#pragma unroll
      for (int n = 0; n < 4; ++n) {
        int col = n0 + wc * 64 + n * 16 + lcol;
        float bv = bias[col];
#pragma unroll
        for (int j = 0; j < 4; ++j) {
          int r = rbase + j;
          float vv = acc[m][n][j] + bv;
          ((unsigned short*)Cout)[z * sCz + (size_t)r * ldc + col] = f2b(vv);
        }
      }
    }
  } else {
    float bv[4];
#pragma unroll
    for (int n = 0; n < 4; ++n) bv[n] = bias[n0 + wc * 64 + n * 16 + lcol];
#pragma unroll
    for (int m = 0; m < 4; ++m) {
#pragma unroll
      for (int j = 0; j < 4; ++j) {
        float x[4];
#pragma unroll
        for (int n = 0; n < 4; ++n) x[n] = acc[m][n][j] + bv[n];
        int rib = wr * 64 + m * 16 + lrow4 + j;
        int r = m0 + rib;
        int b = r & 31, s = r >> 5;
        float* crow = (float*)Cout + (size_t)(b * Ss + s) * ldc;
#pragma unroll
        for (int n = 0; n < 4; ++n)
          __builtin_nontemporal_store(x[n], crow + n0 + wc * 64 + n * 16 + lcol);
        float mx = fmaxf(fmaxf(x[0], x[1]), fmaxf(x[2], x[3]));
#pragma unroll
        for (int msk = 1; msk < 16; msk <<= 1) mx = fmaxf(mx, __shfl_xor(mx, msk, 16));
        float se = __expf(x[0] - mx) + __expf(x[1] - mx) + __expf(x[2] - mx) + __expf(x[3] - mx);
#pragma unroll
        for (int msk = 1; msk < 16; msk <<= 1) se += __shfl_xor(se, msk, 16);
        if (lcol == 0) { smx[rib][wc] = mx; sse[rib][wc] = se; }
      }
    }
    __syncthreads();
    if (t < 128) {
      float ma = smx[t][0], mb = smx[t][1];
      float M = fmaxf(ma, mb);
      float S = sse[t][0] * __expf(ma - M) + sse[t][1] * __expf(mb - M);
      int rg = m0 + t;
      int b = rg & 31, s = rg >> 5;
      size_t orow = (size_t)(b * Ss + s);
      pm[orow * 250 + blockIdx.y] = M;
      ps[orow * 250 + blockIdx.y] = S;
    }
  }
}

// ---------------- persistent recurrence kernel ----------------
// grid = 129 blocks x 384 threads. blk<64: layer1; 64<=blk<128: layer0;
// blk==128: barrier coordinator (polls 128 arrival slots, broadcasts go).
// Weights: held in VGPRs for the whole kernel (loaded once).
// State: staged to LDS per phase via coalesced 8B coherent loads.

#define MFMA16 __builtin_amdgcn_mfma_f32_16x16x32_bf16
#define L1_STRIDE 1544   // 1536 + 8 pad cols (16B); keeps b128 reads bank-balanced
#define L0_STRIDE 520    // 512 + 8

__global__ __launch_bounds__(384, 1) void pers_kernel(
    const unsigned short* __restrict__ gi0,
    const unsigned short* __restrict__ whh0b, const unsigned short* __restrict__ w1cat,
    const float* __restrict__ b_hh0, const float* __restrict__ b_ih1, const float* __restrict__ b_hh1,
    const float* __restrict__ context,
    unsigned short* __restrict__ XH, unsigned short* __restrict__ H0,
    unsigned short* __restrict__ outs, unsigned* bar) {
  extern __shared__ __align__(16) unsigned short A_lds[];
  __shared__ float pre[7][16][33];
  __shared__ float hf[32][16];
  __shared__ float bA[16], bB[16], bC[16], bD[16];
  __shared__ unsigned sAbort;

  unsigned* go = bar;           // bar[0]
  unsigned* arr = bar + 64;     // slot i at arr[i*4] (16B stride)

  const int tid = threadIdx.x, blk = blockIdx.x;

  // ---------- coordinator block ----------
  if (blk == 128) {
    if (tid < 64) {
      for (unsigned v = 1; v <= 130; ++v) {
        ull t0 = __builtin_amdgcn_s_memrealtime();
        bool dead = false;
        while (true) {
          unsigned a0 = __hip_atomic_load(arr + tid * 4, __ATOMIC_RELAXED, __HIP_MEMORY_SCOPE_AGENT);
          unsigned a1 = __hip_atomic_load(arr + (tid + 64) * 4, __ATOMIC_RELAXED, __HIP_MEMORY_SCOPE_AGENT);
          bool ok = (a0 >= v) && (a1 >= v);
          bool to = (__builtin_amdgcn_s_memrealtime() - t0) > 100000000ULL;
          if (__all(ok)) break;
          if (__any(to)) { dead = true; break; }
          __builtin_amdgcn_s_sleep(1);
        }
        if (tid == 0)
          __hip_atomic_store(go, dead ? 0x7FFFFFFFu : v, __ATOMIC_RELAXED, __HIP_MEMORY_SCOPE_AGENT);
        if (dead) return;
      }
    }
    return;
  }

  const int w = tid >> 6, lane = tid & 63, ln = lane & 15;
  const int hi8 = (lane >> 4) * 8;
  const bool isL1 = blk < 64;
  const int d = (blk & 63) >> 5, j0 = (blk & 31) * 16;
  const int g = w >> 1, kh = w & 1;

  // arrival + go-spin barrier. __syncthreads drains all waves' stores first.
  auto wait_go = [&](unsigned v) -> bool {
    __syncthreads();
    if (tid == 0) {
      __hip_atomic_store(arr + blk * 4, v, __ATOMIC_RELAXED, __HIP_MEMORY_SCOPE_AGENT);
      ull t0 = __builtin_amdgcn_s_memrealtime();
      unsigned gv;
      while ((gv = __hip_atomic_load(go, __ATOMIC_RELAXED, __HIP_MEMORY_SCOPE_AGENT)) < v) {
        if ((__builtin_amdgcn_s_memrealtime() - t0) > 100000000ULL) {
          gv = 0x7FFFFFFFu;
          __hip_atomic_store(go, gv, __ATOMIC_RELAXED, __HIP_MEMORY_SCOPE_AGENT);
          break;
        }
        __builtin_amdgcn_s_sleep(1);
      }
      sAbort = (gv == 0x7FFFFFFFu) ? 1u : 0u;
    }
    __syncthreads();
    return sAbort != 0u;
  };

  auto stile = [&](int s, f32x4 v0, f32x4 v1) {
    int c = ln, r0 = (lane >> 4) * 4;
#pragma unroll
    for (int j = 0; j < 4; ++j) {
      pre[s][c][r0 + j] = v0[j];
      pre[s][c][16 + r0 + j] = v1[j];
    }
  };

  // ---- weights -> registers (once) ----
  bf16x8 wreg[24];
  if (isL1) {
    const unsigned short* Bw =
        w1cat + ((size_t)d * 1536 + g * 512 + j0 + ln) * 1536 + kh * 768 + hi8;
#pragma unroll
    for (int i = 0; i < 24; ++i) wreg[i] = *reinterpret_cast<const bf16x8*>(Bw + i * 32);
  } else {
    const unsigned short* Bw =
        whh0b + ((size_t)d * 1536 + g * 512 + j0 + ln) * 512 + kh * 256 + hi8;
#pragma unroll
    for (int i = 0; i < 8; ++i) wreg[i] = *reinterpret_cast<const bf16x8*>(Bw + i * 32);
  }

  // ---- init: biases + h state ----
  if (tid < 16) {
    int jj = tid;
    if (isL1) {
      bA[jj] = b_ih1[d * 1536 + j0 + jj] + b_hh1[d * 1536 + j0 + jj];
      bB[jj] = b_ih1[d * 1536 + 512 + j0 + jj] + b_hh1[d * 1536 + 512 + j0 + jj];
      bC[jj] = b_ih1[d * 1536 + 1024 + j0 + jj];
      bD[jj] = b_hh1[d * 1536 + 1024 + j0 + jj];
    } else {
      bA[jj] = b_hh0[d * 1536 + j0 + jj];
      bB[jj] = b_hh0[d * 1536 + 512 + j0 + jj];
      bC[jj] = b_hh0[d * 1536 + 1024 + j0 + jj];
    }
  }
  {
    int layer = isL1 ? 1 : 0;
    for (int i = tid; i < 128; i += 384) {
      int b = i >> 2, j4 = (i & 3) * 4;
      ull pk = 0;
#pragma unroll
      for (int k = 0; k < 4; ++k) {
        float c = context[(((size_t)layer * 2 + d) * 32 + b) * 512 + j0 + j4 + k];
        hf[b][j4 + k] = c;
        pk |= ((ull)f2b(c)) << (16 * k);
      }
      if (isL1) astore8(XH + (size_t)b * 2048 + 1024 + d * 512 + j0 + j4, pk);          // parity 0
      else      astore8(H0 + (size_t)32768 + ((size_t)d * 32 + b) * 512 + j0 + j4, pk); // parity 1
    }
  }
  if (wait_go(1)) return;

  // ---- phase loop ----
  for (int p = 0; p <= 128; ++p) {
    ull gr = 0, gz2 = 0, gn2 = 0;

    // stage state -> LDS (+ L0: prefetch gi0 into regs)
    if (isL1) {
      if (p >= 1) {
        const unsigned short* XHp = XH + (size_t)((p - 1) & 1) * 65536;
        int col = tid * 4;
        int gcol = (col < 1024) ? col : (1024 + d * 512 + (col - 1024));
        const unsigned short* src = XHp + gcol;
        unsigned short* dstl = A_lds + col;
        ull v[32];
#pragma unroll
        for (int b = 0; b < 32; ++b) v[b] = aload8(src + (size_t)b * 2048);
#pragma unroll
        for (int b = 0; b < 32; ++b) *(ull*)(dstl + b * L1_STRIDE) = v[b];
      }
    } else {
      if (p <= 127) {
        if (tid < 128) {
          const unsigned short* gzp =
              gi0 + ((size_t)d * 128 + p) * 32 * 1536 + (size_t)(tid >> 2) * 1536 + j0 + (tid & 3) * 4;
          gr  = *(const ull*)(gzp);
          gz2 = *(const ull*)(gzp + 512);
          gn2 = *(const ull*)(gzp + 1024);
        }
        const unsigned short* H0p =
            H0 + (size_t)((p + 1) & 1) * 32768 + (size_t)d * 32 * 512;
        ull v[11];
#pragma unroll
        for (int k = 0; k < 11; ++k) {
          int idx = tid + k * 384;
          if (idx < 4096) v[k] = aload8(H0p + (size_t)(idx >> 7) * 512 + (idx & 127) * 4);
        }
#pragma unroll
        for (int k = 0; k < 11; ++k) {
          int idx = tid + k * 384;
          if (idx < 4096) *(ull*)(A_lds + (idx >> 7) * L0_STRIDE + (idx & 127) * 4) = v[k];
        }
      }
    }
    __syncthreads();

    // MFMA from LDS x register weights
    if (isL1) {
      if (p >= 1) {
        f32x4 p0 = {}, p1 = {}, q0 = {}, q1 = {};
        const unsigned short* al = A_lds + kh * 768 + hi8;
        if (g == 2 && kh == 1) {
#pragma unroll
          for (int i = 0; i < 8; ++i) {
            bf16x8 a0 = *reinterpret_cast<const bf16x8*>(al + ln * L1_STRIDE + i * 32);
            bf16x8 a1 = *reinterpret_cast<const bf16x8*>(al + (ln + 16) * L1_STRIDE + i * 32);
            p0 = MFMA16(a0, wreg[i], p0, 0, 0, 0);
            p1 = MFMA16(a1, wreg[i], p1, 0, 0, 0);
          }
#pragma unroll
          for (int i = 8; i < 24; ++i) {
            bf16x8 a0 = *reinterpret_cast<const bf16x8*>(al + ln * L1_STRIDE + i * 32);
            bf16x8 a1 = *reinterpret_cast<const bf16x8*>(al + (ln + 16) * L1_STRIDE + i * 32);
            q0 = MFMA16(a0, wreg[i], q0, 0, 0, 0);
            q1 = MFMA16(a1, wreg[i], q1, 0, 0, 0);
          }
          stile(5, p0, p1);
          stile(6, q0, q1);
        } else {
#pragma unroll
          for (int i = 0; i < 24; ++i) {
            bf16x8 a0 = *reinterpret_cast<const bf16x8*>(al + ln * L1_STRIDE + i * 32);
            bf16x8 a1 = *reinterpret_cast<const bf16x8*>(al + (ln + 16) * L1_STRIDE + i * 32);
            p0 = MFMA16(a0, wreg[i], p0, 0, 0, 0);
            p1 = MFMA16(a1, wreg[i], p1, 0, 0, 0);
          }
          stile((g < 2) ? g * 2 + kh : 4, p0, p1);
        }
      }
    } else {
      if (p <= 127) {
        f32x4 p0 = {}, p1 = {};
        const unsigned short* al = A_lds + kh * 256 + hi8;
#pragma unroll
        for (int i = 0; i < 8; ++i) {
          bf16x8 a0 = *reinterpret_cast<const bf16x8*>(al + ln * L0_STRIDE + i * 32);
          bf16x8 a1 = *reinterpret_cast<const bf16x8*>(al + (ln + 16) * L0_STRIDE + i * 32);
          p0 = MFMA16(a0, wreg[i], p0, 0, 0, 0);
          p1 = MFMA16(a1, wreg[i], p1, 0, 0, 0);
        }
        stile((g < 2) ? g * 2 + kh : 4 + kh, p0, p1);
      }
    }
    __syncthreads();

    // nonlinearity + state stores
    if (isL1) {
      if (p >= 1 && tid < 128) {
        int t_ = p - 1;
        int b = tid >> 2, j4 = (tid & 3) * 4;
        ull pk = 0;
#pragma unroll
        for (int k = 0; k < 4; ++k) {
          int jj = j4 + k;
          float r = sigm(pre[0][jj][b] + pre[1][jj][b] + bA[jj]);
          float z = sigm(pre[2][jj][b] + pre[3][jj][b] + bB[jj]);
          float nn = tanhf(pre[4][jj][b] + pre[5][jj][b] + bC[jj] +
                           r * (pre[6][jj][b] + bD[jj]));
          float h = hf[b][jj];
          float hnew = (1.f - z) * nn + z * h;
          hf[b][jj] = hnew;
          pk |= ((ull)f2b(hnew)) << (16 * k);
        }
        astore8(XH + (size_t)(p & 1) * 65536 + (size_t)b * 2048 + 1024 + d * 512 + j0 + j4, pk);
        __builtin_nontemporal_store(
            pk, (ull*)(outs + ((size_t)t_ * 32 + b) * 1024 + (size_t)d * 512 + j0 + j4));
      }
    } else {
      if (p <= 127 && tid < 128) {
        int b = tid >> 2, j4 = (tid & 3) * 4;
        int col = j0 + j4;
        ull pk = 0;
#pragma unroll
        for (int k = 0; k < 4; ++k) {
          int jj = j4 + k;
          float gir = b2f((unsigned short)(gr >> (16 * k)));
          float giz = b2f((unsigned short)(gz2 >> (16 * k)));
          float gin = b2f((unsigned short)(gn2 >> (16 * k)));
          float r = sigm(gir + pre[0][jj][b] + pre[1][jj][b] + bA[jj]);
          float z = sigm(giz + pre[2][jj][b] + pre[3][jj][b] + bB[jj]);
          float nn = tanhf(gin + r * (pre[4][jj][b] + pre[5][jj][b] + bC[jj]));
          float h = hf[b][jj];
          float hnew = (1.f - z) * nn + z * h;
          hf[b][jj] = hnew;
          pk |= ((ull)f2b(hnew)) << (16 * k);
        }
        astore8(H0 + (size_t)(p & 1) * 32768 + ((size_t)d * 32 + b) * 512 + col, pk);
        astore8(XH + (size_t)(p & 1) * 65536 + (size_t)b * 2048 + d * 512 + col, pk);
      }
    }
    if (wait_go((unsigned)(p + 2))) return;
  }
}

// ---------------- log-softmax: partial reduce + subtract ----------------

__global__ __launch_bounds__(128) void lse_reduce(const float* __restrict__ pm,
                                                  const float* __restrict__ ps,
                                                  float* __restrict__ lsebuf) {
  int r = blockIdx.x * 128 + threadIdx.x;
  const float* pmr = pm + (size_t)r * 250;
  const float* psr = ps + (size_t)r * 250;
  float M = -1e30f, S = 0.f;
  for (int i = 0; i < 250; ++i) {
    float m2 = pmr[i], s2 = psr[i];
    if (m2 <= M) {
      S += s2 * __expf(m2 - M);
    } else {
      S = S * __expf(M - m2) + s2;
      M = m2;
    }
  }
  lsebuf[r] = M + __logf(S);
}

__global__ __launch_bounds__(256) void sub_lse(float* __restrict__ out,
                                               const float* __restrict__ lsebuf) {
  int row = blockIdx.x;
  float l = lsebuf[row];
  f32x4* rp = (f32x4*)(out + (size_t)row * Vv);
  for (int i = threadIdx.x; i < 8000; i += 256) {
    f32x4 v = __builtin_nontemporal_load(rp + i);
    v[0] -= l; v[1] -= l; v[2] -= l; v[3] -= l;
    __builtin_nontemporal_store(v, rp + i);
  }
}

// ---------------- host ----------------

extern "C" void kernel_launch(void* const* d_in, const int* in_sizes, int n_in,
                              void* d_out, int out_size, void* d_ws, size_t ws_size,
                              hipStream_t stream) {
  (void)in_sizes; (void)n_in; (void)out_size; (void)ws_size;
  const int*   target  = (const int*)  d_in[0];
  const float* context = (const float*)d_in[2];
  const float* table   = (const float*)d_in[3];
  const float* w_ih0   = (const float*)d_in[4];
  const float* w_hh0   = (const float*)d_in[5];
  const float* b_ih0   = (const float*)d_in[6];
  const float* b_hh0   = (const float*)d_in[7];
  const float* w_ih1   = (const float*)d_in[8];
  const float* w_hh1   = (const float*)d_in[9];
  const float* b_ih1   = (const float*)d_in[10];
  const float* b_hh1   = (const float*)d_in[11];
  const float* fc_w    = (const float*)d_in[12];
  const float* fc_b    = (const float*)d_in[13];
  float* out = (float*)d_out;

  uint8_t* ws = (uint8_t*)d_ws;
  size_t off = 0;
  auto alloc = [&](size_t bytes) {
    uint8_t* p = ws + off;
    off += (bytes + 255) & ~(size_t)255;
    return p;
  };
  unsigned*       bar   = (unsigned*)alloc(4096);
  unsigned short* XH    = (unsigned short*)alloc((size_t)2 * 32 * 2048 * 2);
  unsigned short* H0    = (unsigned short*)alloc((size_t)2 * 2 * 32 * 512 * 2);
  unsigned short* whh0b = (unsigned short*)alloc((size_t)1572864 * 2);
  unsigned short* w1cat = (unsigned short*)alloc((size_t)2 * 1536 * 1536 * 2);
  unsigned short* embb  = (unsigned short*)alloc((size_t)2097152 * 2);
  unsigned short* wih0b = (unsigned short*)alloc((size_t)1572864 * 2);
  unsigned short* gi0   = (unsigned short*)alloc((size_t)12582912 * 2);
  unsigned short* outsb = (unsigned short*)alloc((size_t)4194304 * 2);
  unsigned short* fcwb  = (unsigned short*)alloc((size_t)32768000 * 2);

  // partials + lse overlay gi0's region (dead after pers_kernel)
  float* pm     = (float*)gi0;
  float* ps     = pm + (size_t)4096 * 250;
  float* lsebuf = ps + (size_t)4096 * 250;

  // allow >64KB dynamic LDS for pers_kernel (immediate call, capture-safe)
  static bool attr_done = false;
  if (!attr_done) {
    hipFuncSetAttribute(reinterpret_cast<const void*>(pers_kernel),
                        hipFuncAttributeMaxDynamicSharedMemorySize, 98816);
    attr_done = true;
  }

  // prep
  zero_flags<<<dim3(1), 256, 0, stream>>>(bar);
  cast_bf16<<<dim3(1536), 256, 0, stream>>>(w_ih0, wih0b, 393216);
  cast_bf16<<<dim3(1536), 256, 0, stream>>>(w_hh0, whh0b, 393216);
  cast_bf16<<<dim3(32000), 256, 0, stream>>>(fc_w, fcwb, 8192000);
  pack_w1<<<dim3(3072), 256, 0, stream>>>(w_ih1, w_hh1, w1cat);
  embed_gather<<<dim3(4096), 128, 0, stream>>>(target, table, embb);

  // gi0 = emb * w_ih0^T + b_ih0  (bf16 out [d][4096][1536])
  gemm_nt<0><<<dim3(32, 12, 2), 256, 0, stream>>>(
      embb, wih0b, b_ih0, gi0, 512, 1536,
      (size_t)1536 * 512, (size_t)4096 * 1536, (size_t)1536, nullptr, nullptr);

  // recurrence: one persistent kernel, flag barrier, 129 blocks + coordinator
  pers_kernel<<<dim3(129), 384, 98816, stream>>>(
      gi0, whh0b, w1cat, b_hh0, b_ih1, b_hh1, context, XH, H0, outsb, bar);

  // logits = outs * fc_w^T + fc_b  (row remap (s,b)->(b,s)) + LSE partials
  gemm_nt<1><<<dim3(32, 250, 1), 256, 0, stream>>>(
      outsb, fcwb, fc_b, out, 1024, Vv, 0, 0, 0, pm, ps);

  // log_softmax: reduce partials then subtract
  lse_reduce<<<dim3(32), 128, 0, stream>>>(pm, ps, lsebuf);
  sub_lse<<<dim3(4096), 256, 0, stream>>>(out, lsebuf);
}

// Round 5
// 1356.500 us; speedup vs baseline: 3.1761x; 1.0148x over previous
//
#include <hip/hip_runtime.h>
#include <cstdint>
#include <cstddef>

#define Vv 32000
#define Ee 512
#define Hh 512
#define Bb 32
#define Ss 128

typedef __bf16 bf16x8 __attribute__((ext_vector_type(8)));
typedef float  f32x4  __attribute__((ext_vector_type(4)));
typedef unsigned long long ull;

__device__ __forceinline__ float b2f(unsigned short u) {
  union { unsigned int i; float f; } v; v.i = ((unsigned int)u) << 16; return v.f;
}
__device__ __forceinline__ unsigned short f2b(float f) {
  union { float f; unsigned int i; } v; v.f = f;
  unsigned int r = v.i + 0x7FFFu + ((v.i >> 16) & 1u);
  return (unsigned short)(r >> 16);
}
__device__ __forceinline__ float sigm(float x) { return 1.f / (1.f + __expf(-x)); }

// Cross-XCD coherent 8B ops (sc1 path through the coherence point).
__device__ __forceinline__ ull aload8(const unsigned short* p) {
  return __hip_atomic_load((const ull*)p, __ATOMIC_RELAXED, __HIP_MEMORY_SCOPE_AGENT);
}
__device__ __forceinline__ void astore8(unsigned short* p, ull v) {
  __hip_atomic_store((ull*)p, v, __ATOMIC_RELAXED, __HIP_MEMORY_SCOPE_AGENT);
}

// async global->LDS, 16B per lane; lds dest = wave-uniform base + lane*16
__device__ __forceinline__ void gl_lds16(const unsigned short* g, unsigned short* l) {
  __builtin_amdgcn_global_load_lds(
      (const __attribute__((address_space(1))) void*)g,
      (__attribute__((address_space(3))) void*)l, 16, 0, 0);
}

// ---------------- prep kernels ----------------

__global__ void zero_flags(unsigned* p) {
  for (int i = threadIdx.x; i < 4096; i += 256) p[i] = 0u;
}

__global__ void cast_bf16(const float* __restrict__ src, unsigned short* __restrict__ dst, int n4) {
  int i = blockIdx.x * 256 + threadIdx.x;
  if (i >= n4) return;
  float4 v = reinterpret_cast<const float4*>(src)[i];
  ushort4 o;
  o.x = f2b(v.x); o.y = f2b(v.y); o.z = f2b(v.z); o.w = f2b(v.w);
  reinterpret_cast<ushort4*>(dst)[i] = o;
}

// w1cat[d][n][0..1023] = w_ih1[d][n][*]; [1024..1535] = w_hh1[d][n][*]
__global__ void pack_w1(const float* __restrict__ ih, const float* __restrict__ hh,
                        unsigned short* __restrict__ dst) {
  int r = blockIdx.x;  // d*1536 + n
  const float* si = ih + (size_t)r * 1024;
  const float* sh = hh + (size_t)r * 512;
  unsigned short* dr = dst + (size_t)r * 1536;
  for (int c = threadIdx.x; c < 1024; c += 256) dr[c] = f2b(si[c]);
  for (int c = threadIdx.x; c < 512; c += 256) dr[1024 + c] = f2b(sh[c]);
}

// emb_bf16[s][b][e]
__global__ void embed_gather(const int* __restrict__ target, const float* __restrict__ table,
                             unsigned short* __restrict__ emb) {
  int sb = blockIdx.x;           // s*32 + b
  int s = sb >> 5, b = sb & 31;
  int tok = target[b * Ss + s];
  float4 v = reinterpret_cast<const float4*>(table + (size_t)tok * Ee)[threadIdx.x];
  ushort4 o;
  o.x = f2b(v.x); o.y = f2b(v.y); o.z = f2b(v.z); o.w = f2b(v.w);
  reinterpret_cast<ushort4*>(emb + (size_t)sb * Ee)[threadIdx.x] = o;
}

// ---------------- bf16 MFMA GEMM: C = A * B^T + bias ----------------
// MODE 0: C bf16 [M][ldc], row = A-row; z via sBz/sCz/sBiasz (grid.z)
// MODE 1: C f32, row remap r=(s*32+b) -> out row (b*128+s), ldc=Vv,
//         nontemporal C stores + fused per-(row,colblock) max/sumexp partials,
//         XCD-swizzled block mapping for B-panel L2 locality.
template <int MODE>
__global__ __launch_bounds__(256, 2) void gemm_nt(
    const unsigned short* __restrict__ A, const unsigned short* __restrict__ Bm,
    const float* __restrict__ bias, void* __restrict__ Cout,
    int K, int ldc, size_t sBz, size_t sCz, size_t sBiasz,
    float* __restrict__ pm, float* __restrict__ ps) {
  int z = blockIdx.z;
  Bm += z * sBz;
  bias += z * sBiasz;

  __shared__ __align__(16) unsigned short As[128 * 64];
  __shared__ __align__(16) unsigned short Bs[128 * 64];
  __shared__ float smx[128][2], sse[128][2];

  int t = threadIdx.x;
  int bx, by;
  if (MODE == 1) {
    // bijective XCD swizzle: 8000 blocks, 1000 consecutive tiles per XCD
    int lin = blockIdx.x + (int)gridDim.x * blockIdx.y;
    int q = (int)(gridDim.x * gridDim.y) >> 3;
    int wg = (lin & 7) * q + (lin >> 3);
    bx = wg & 31; by = wg >> 5;
  } else {
    bx = blockIdx.x; by = blockIdx.y;
  }
  int m0 = bx * 128, n0 = by * 128;
  int wave = t >> 6, lane = t & 63;
  int wr = wave >> 1, wc = wave & 1;

  f32x4 acc[4][4] = {};

  int kt = K >> 6;
  for (int ks = 0; ks < kt; ++ks) {
    int k0 = ks << 6;
#pragma unroll
    for (int c = 0; c < 4; ++c) {
      int v = c * 256 + t;
      int row = v >> 3, col = (v & 7) * 8;
      int vb = (c * 256 + (t & 192)) * 8;  // wave-uniform LDS base (ushorts)
      gl_lds16(A + (size_t)(m0 + row) * K + k0 + col, As + vb);
      gl_lds16(Bm + (size_t)(n0 + row) * K + k0 + col, Bs + vb);
    }
    __syncthreads();
#pragma unroll
    for (int kk = 0; kk < 2; ++kk) {
      bf16x8 af[4], bfr[4];
      int lrow = lane & 15, lk = kk * 32 + (lane >> 4) * 8;
#pragma unroll
      for (int m = 0; m < 4; ++m)
        af[m] = *reinterpret_cast<const bf16x8*>(As + (wr * 64 + m * 16 + lrow) * 64 + lk);
#pragma unroll
      for (int n = 0; n < 4; ++n)
        bfr[n] = *reinterpret_cast<const bf16x8*>(Bs + (wc * 64 + n * 16 + lrow) * 64 + lk);
#pragma unroll
      for (int m = 0; m < 4; ++m)
#pragma unroll
        for (int n = 0; n < 4; ++n)
          acc[m][n] = __builtin_amdgcn_mfma_f32_16x16x32_bf16(af[m], bfr[n], acc[m][n], 0, 0, 0);
    }
    __syncthreads();
  }

  int lrow4 = (lane >> 4) * 4, lcol = lane & 15;
  if (MODE == 0) {
#pragma unroll
    for (int m = 0; m < 4; ++m) {
      int rbase = m0 + wr * 64 + m * 16 + lrow4;
#pragma unroll
      for (int n = 0; n < 4; ++n) {
        int col = n0 + wc * 64 + n * 16 + lcol;
        float bv = bias[col];
#pragma unroll
        for (int j = 0; j < 4; ++j) {
          int r = rbase + j;
          float vv = acc[m][n][j] + bv;
          ((unsigned short*)Cout)[z * sCz + (size_t)r * ldc + col] = f2b(vv);
        }
      }
    }
  } else {
    float bv[4];
#pragma unroll
    for (int n = 0; n < 4; ++n) bv[n] = bias[n0 + wc * 64 + n * 16 + lcol];
#pragma unroll
    for (int m = 0; m < 4; ++m) {
#pragma unroll
      for (int j = 0; j < 4; ++j) {
        float x[4];
#pragma unroll
        for (int n = 0; n < 4; ++n) x[n] = acc[m][n][j] + bv[n];
        int rib = wr * 64 + m * 16 + lrow4 + j;
        int r = m0 + rib;
        int b = r & 31, s = r >> 5;
        float* crow = (float*)Cout + (size_t)(b * Ss + s) * ldc;
#pragma unroll
        for (int n = 0; n < 4; ++n)
          __builtin_nontemporal_store(x[n], crow + n0 + wc * 64 + n * 16 + lcol);
        float mx = fmaxf(fmaxf(x[0], x[1]), fmaxf(x[2], x[3]));
#pragma unroll
        for (int msk = 1; msk < 16; msk <<= 1) mx = fmaxf(mx, __shfl_xor(mx, msk, 16));
        float se = __expf(x[0] - mx) + __expf(x[1] - mx) + __expf(x[2] - mx) + __expf(x[3] - mx);
#pragma unroll
        for (int msk = 1; msk < 16; msk <<= 1) se += __shfl_xor(se, msk, 16);
        if (lcol == 0) { smx[rib][wc] = mx; sse[rib][wc] = se; }
      }
    }
    __syncthreads();
    if (t < 128) {
      float ma = smx[t][0], mb = smx[t][1];
      float M = fmaxf(ma, mb);
      float S = sse[t][0] * __expf(ma - M) + sse[t][1] * __expf(mb - M);
      int rg = m0 + t;
      int b = rg & 31, s = rg >> 5;
      size_t orow = (size_t)(b * Ss + s);
      pm[orow * 250 + by] = M;
      ps[orow * 250 + by] = S;
    }
  }
}

// ---------------- persistent recurrence kernel ----------------
// grid = 128 blocks x 384 threads. blk<64: layer1; 64<=blk<128: layer0.
// Direct flag sync, no coordinator. flag[blk] (64B stride) = phases done + 1.
// State buffers mod-4 deep: phase p writes slot p&3, reads slot (p-1)&3.
// Deps: L0-d polls 32 L0-d sibs >= p+1 (fwd) + 64 L1 >= p-1 (backpressure);
//       L1-d polls 64 L0 >= p+1 + 32 L1-d sibs >= p+1. L0 runs ~2 phases
//       ahead in steady state so L1's polls are pre-satisfied.

#define MFMA16 __builtin_amdgcn_mfma_f32_16x16x32_bf16
#define L1_STRIDE 1544   // 1536 + 8 pad
#define L0_STRIDE 520    // 512 + 8

__global__ __launch_bounds__(384, 1) void pers_kernel(
    const unsigned short* __restrict__ gi0,
    const unsigned short* __restrict__ whh0b, const unsigned short* __restrict__ w1cat,
    const float* __restrict__ b_hh0, const float* __restrict__ b_ih1, const float* __restrict__ b_hh1,
    const float* __restrict__ context,
    unsigned short* __restrict__ XH, unsigned short* __restrict__ H0,
    unsigned short* __restrict__ outs, unsigned* bar) {
  extern __shared__ __align__(16) unsigned short A_lds[];
  __shared__ float pre[7][16][33];
  __shared__ float hf[32][16];
  __shared__ float bA[16], bB[16], bC[16], bD[16];
  __shared__ unsigned sAbort;

  unsigned* flags = bar;           // flag[i] at bar[i*16]
  unsigned* abortf = bar + 3072;

  const int tid = threadIdx.x, blk = blockIdx.x;
  const int w = tid >> 6, lane = tid & 63, ln = lane & 15;
  const int hi8 = (lane >> 4) * 8;
  const bool isL1 = blk < 64;
  const int d = (blk & 63) >> 5, j0 = (blk & 31) * 16;
  const int g = w >> 1, kh = w & 1;

  if (tid == 0) sAbort = 0u;

  auto stile = [&](int s, f32x4 v0, f32x4 v1) {
    int c = ln, r0 = (lane >> 4) * 4;
#pragma unroll
    for (int j = 0; j < 4; ++j) {
      pre[s][c][r0 + j] = v0[j];
      pre[s][c][16 + r0 + j] = v1[j];
    }
  };

  // ---- weights -> registers (once) ----
  bf16x8 wreg[24];
  if (isL1) {
    const unsigned short* Bw =
        w1cat + ((size_t)d * 1536 + g * 512 + j0 + ln) * 1536 + kh * 768 + hi8;
#pragma unroll
    for (int i = 0; i < 24; ++i) wreg[i] = *reinterpret_cast<const bf16x8*>(Bw + i * 32);
  } else {
    const unsigned short* Bw =
        whh0b + ((size_t)d * 1536 + g * 512 + j0 + ln) * 512 + kh * 256 + hi8;
#pragma unroll
    for (int i = 0; i < 8; ++i) wreg[i] = *reinterpret_cast<const bf16x8*>(Bw + i * 32);
  }

  // ---- init: biases + h state ----
  if (tid < 16) {
    int jj = tid;
    if (isL1) {
      bA[jj] = b_ih1[d * 1536 + j0 + jj] + b_hh1[d * 1536 + j0 + jj];
      bB[jj] = b_ih1[d * 1536 + 512 + j0 + jj] + b_hh1[d * 1536 + 512 + j0 + jj];
      bC[jj] = b_ih1[d * 1536 + 1024 + j0 + jj];
      bD[jj] = b_hh1[d * 1536 + 1024 + j0 + jj];
    } else {
      bA[jj] = b_hh0[d * 1536 + j0 + jj];
      bB[jj] = b_hh0[d * 1536 + 512 + j0 + jj];
      bC[jj] = b_hh0[d * 1536 + 1024 + j0 + jj];
    }
  }
  {
    int layer = isL1 ? 1 : 0;
    for (int i = tid; i < 128; i += 384) {
      int b = i >> 2, j4 = (i & 3) * 4;
      ull pk = 0;
#pragma unroll
      for (int k = 0; k < 4; ++k) {
        float c = context[(((size_t)layer * 2 + d) * 32 + b) * 512 + j0 + j4 + k];
        hf[b][j4 + k] = c;
        pk |= ((ull)f2b(c)) << (16 * k);
      }
      // h1(-1) -> XH slot 0 (read at phase 1); h0(-1) -> H0 slot 3 (read at phase 0)
      if (isL1) astore8(XH + (size_t)b * 2048 + 1024 + d * 512 + j0 + j4, pk);
      else      astore8(H0 + (size_t)3 * 32768 + ((size_t)d * 32 + b) * 512 + j0 + j4, pk);
    }
  }
  __syncthreads();  // drains init stores (vmcnt 0 per wave)
  if (tid == 0)
    __hip_atomic_store(flags + (size_t)blk * 16, 1u, __ATOMIC_RELAXED, __HIP_MEMORY_SCOPE_AGENT);

  // ---- phase loop ----
  for (int p = 0; p <= 128; ++p) {
    // L0: prefetch gi0 registers (independent of sync)
    ull gr = 0, gz2 = 0, gn2 = 0;
    if (!isL1 && p <= 127 && tid < 128) {
      const unsigned short* gzp =
          gi0 + ((size_t)d * 128 + p) * 32 * 1536 + (size_t)(tid >> 2) * 1536 + j0 + (tid & 3) * 4;
      gr  = *(const ull*)(gzp);
      gz2 = *(const ull*)(gzp + 512);
      gn2 = *(const ull*)(gzp + 1024);
    }

    // ---- poll deps (waves 0,1) ----
    if (w < 2) {
      int idx = -1, tgt = 0;
      if (isL1) {
        if (w == 0) { if (lane < 64) { idx = 64 + lane; tgt = p + 1; } }
        else        { if (lane < 32) { idx = d * 32 + lane; tgt = p + 1; } }
      } else {
        if (w == 0) { if (lane < 32) { idx = 64 + d * 32 + lane; tgt = p + 1; } }
        else        { if (lane < 64) { idx = lane; tgt = p - 1; } }
      }
      ull t0 = __builtin_amdgcn_s_memrealtime();
      while (true) {
        int f = (idx >= 0)
            ? (int)__hip_atomic_load(flags + (size_t)idx * 16, __ATOMIC_RELAXED, __HIP_MEMORY_SCOPE_AGENT)
            : 0x7FFFFFF;
        if (__all(f >= tgt)) break;
        if ((__builtin_amdgcn_s_memrealtime() - t0) > 100000000ULL ||
            __hip_atomic_load(abortf, __ATOMIC_RELAXED, __HIP_MEMORY_SCOPE_AGENT) != 0u) {
          __hip_atomic_store(abortf, 1u, __ATOMIC_RELAXED, __HIP_MEMORY_SCOPE_AGENT);
          sAbort = 1u;
          break;
        }
        __builtin_amdgcn_s_sleep(1);
      }
    }
    __syncthreads();
    if (sAbort) return;

    int rs = (p - 1) & 3, wslot = p & 3;

    // ---- stage state -> LDS ----
    if (isL1) {
      if (p >= 1) {
        const unsigned short* XHp = XH + (size_t)rs * 65536;
        int col = tid * 4;
        int gcol = (col < 1024) ? col : (1024 + d * 512 + (col - 1024));
        const unsigned short* src = XHp + gcol;
        unsigned short* dstl = A_lds + col;
        ull v[32];
#pragma unroll
        for (int b = 0; b < 32; ++b) v[b] = aload8(src + (size_t)b * 2048);
#pragma unroll
        for (int b = 0; b < 32; ++b) *(ull*)(dstl + b * L1_STRIDE) = v[b];
      }
    } else {
      if (p <= 127) {
        const unsigned short* H0p = H0 + (size_t)rs * 32768 + (size_t)d * 32 * 512;
        ull v[11];
#pragma unroll
        for (int k = 0; k < 11; ++k) {
          int idx = tid + k * 384;
          if (idx < 4096) v[k] = aload8(H0p + (size_t)(idx >> 7) * 512 + (idx & 127) * 4);
        }
#pragma unroll
        for (int k = 0; k < 11; ++k) {
          int idx = tid + k * 384;
          if (idx < 4096) *(ull*)(A_lds + (idx >> 7) * L0_STRIDE + (idx & 127) * 4) = v[k];
        }
      }
    }
    __syncthreads();

    // ---- MFMA from LDS x register weights ----
    if (isL1) {
      if (p >= 1) {
        f32x4 p0 = {}, p1 = {}, q0 = {}, q1 = {};
        const unsigned short* al = A_lds + kh * 768 + hi8;
        if (g == 2 && kh == 1) {
#pragma unroll
          for (int i = 0; i < 8; ++i) {
            bf16x8 a0 = *reinterpret_cast<const bf16x8*>(al + ln * L1_STRIDE + i * 32);
            bf16x8 a1 = *reinterpret_cast<const bf16x8*>(al + (ln + 16) * L1_STRIDE + i * 32);
            p0 = MFMA16(a0, wreg[i], p0, 0, 0, 0);
            p1 = MFMA16(a1, wreg[i], p1, 0, 0, 0);
          }
#pragma unroll
          for (int i = 8; i < 24; ++i) {
            bf16x8 a0 = *reinterpret_cast<const bf16x8*>(al + ln * L1_STRIDE + i * 32);
            bf16x8 a1 = *reinterpret_cast<const bf16x8*>(al + (ln + 16) * L1_STRIDE + i * 32);
            q0 = MFMA16(a0, wreg[i], q0, 0, 0, 0);
            q1 = MFMA16(a1, wreg[i], q1, 0, 0, 0);
          }
          stile(5, p0, p1);
          stile(6, q0, q1);
        } else {
#pragma unroll
          for (int i = 0; i < 24; ++i) {
            bf16x8 a0 = *reinterpret_cast<const bf16x8*>(al + ln * L1_STRIDE + i * 32);
            bf16x8 a1 = *reinterpret_cast<const bf16x8*>(al + (ln + 16) * L1_STRIDE + i * 32);
            p0 = MFMA16(a0, wreg[i], p0, 0, 0, 0);
            p1 = MFMA16(a1, wreg[i], p1, 0, 0, 0);
          }
          stile((g < 2) ? g * 2 + kh : 4, p0, p1);
        }
      }
    } else {
      if (p <= 127) {
        f32x4 p0 = {}, p1 = {};
        const unsigned short* al = A_lds + kh * 256 + hi8;
#pragma unroll
        for (int i = 0; i < 8; ++i) {
          bf16x8 a0 = *reinterpret_cast<const bf16x8*>(al + ln * L0_STRIDE + i * 32);
          bf16x8 a1 = *reinterpret_cast<const bf16x8*>(al + (ln + 16) * L0_STRIDE + i * 32);
          p0 = MFMA16(a0, wreg[i], p0, 0, 0, 0);
          p1 = MFMA16(a1, wreg[i], p1, 0, 0, 0);
        }
        stile((g < 2) ? g * 2 + kh : 4 + kh, p0, p1);
      }
    }
    __syncthreads();

    // ---- nonlinearity + state stores ----
    if (isL1) {
      if (p >= 1 && tid < 128) {
        int t_ = p - 1;
        int b = tid >> 2, j4 = (tid & 3) * 4;
        ull pk = 0;
#pragma unroll
        for (int k = 0; k < 4; ++k) {
          int jj = j4 + k;
          float r = sigm(pre[0][jj][b] + pre[1][jj][b] + bA[jj]);
          float z = sigm(pre[2][jj][b] + pre[3][jj][b] + bB[jj]);
          float nn = tanhf(pre[4][jj][b] + pre[5][jj][b] + bC[jj] +
                           r * (pre[6][jj][b] + bD[jj]));
          float h = hf[b][jj];
          float hnew = (1.f - z) * nn + z * h;
          hf[b][jj] = hnew;
          pk |= ((ull)f2b(hnew)) << (16 * k);
        }
        astore8(XH + (size_t)wslot * 65536 + (size_t)b * 2048 + 1024 + d * 512 + j0 + j4, pk);
        __builtin_nontemporal_store(
            pk, (ull*)(outs + ((size_t)t_ * 32 + b) * 1024 + (size_t)d * 512 + j0 + j4));
      }
    } else {
      if (p <= 127 && tid < 128) {
        int b = tid >> 2, j4 = (tid & 3) * 4;
        int col = j0 + j4;
        ull pk = 0;
#pragma unroll
        for (int k = 0; k < 4; ++k) {
          int jj = j4 + k;
          float gir = b2f((unsigned short)(gr >> (16 * k)));
          float giz = b2f((unsigned short)(gz2 >> (16 * k)));
          float gin = b2f((unsigned short)(gn2 >> (16 * k)));
          float r = sigm(gir + pre[0][jj][b] + pre[1][jj][b] + bA[jj]);
          float z = sigm(giz + pre[2][jj][b] + pre[3][jj][b] + bB[jj]);
          float nn = tanhf(gin + r * (pre[4][jj][b] + pre[5][jj][b] + bC[jj]));
          float h = hf[b][jj];
          float hnew = (1.f - z) * nn + z * h;
          hf[b][jj] = hnew;
          pk |= ((ull)f2b(hnew)) << (16 * k);
        }
        astore8(H0 + (size_t)wslot * 32768 + ((size_t)d * 32 + b) * 512 + col, pk);
        astore8(XH + (size_t)wslot * 65536 + (size_t)b * 2048 + d * 512 + col, pk);
      }
    }
    __syncthreads();  // drains all state stores (vmcnt 0 per wave)
    if (tid == 0)
      __hip_atomic_store(flags + (size_t)blk * 16, (unsigned)(p + 2),
                         __ATOMIC_RELAXED, __HIP_MEMORY_SCOPE_AGENT);
    if (!isL1 && p == 127) return;  // L0 done; flag 129 already satisfies L1 phase 128
  }
}

// ---------------- log-softmax: partial reduce + subtract ----------------

__global__ __launch_bounds__(128) void lse_reduce(const float* __restrict__ pm,
                                                  const float* __restrict__ ps,
                                                  float* __restrict__ lsebuf) {
  int r = blockIdx.x * 128 + threadIdx.x;
  const float* pmr = pm + (size_t)r * 250;
  const float* psr = ps + (size_t)r * 250;
  float M = -1e30f, S = 0.f;
  for (int i = 0; i < 250; ++i) {
    float m2 = pmr[i], s2 = psr[i];
    if (m2 <= M) {
      S += s2 * __expf(m2 - M);
    } else {
      S = S * __expf(M - m2) + s2;
      M = m2;
    }
  }
  lsebuf[r] = M + __logf(S);
}

__global__ __launch_bounds__(256) void sub_lse(float* __restrict__ out,
                                               const float* __restrict__ lsebuf) {
  int row = blockIdx.x;
  float l = lsebuf[row];
  f32x4* rp = (f32x4*)(out + (size_t)row * Vv);
  for (int i = threadIdx.x; i < 8000; i += 256) {
    f32x4 v = __builtin_nontemporal_load(rp + i);
    v[0] -= l; v[1] -= l; v[2] -= l; v[3] -= l;
    __builtin_nontemporal_store(v, rp + i);
  }
}

// ---------------- host ----------------

extern "C" void kernel_launch(void* const* d_in, const int* in_sizes, int n_in,
                              void* d_out, int out_size, void* d_ws, size_t ws_size,
                              hipStream_t stream) {
  (void)in_sizes; (void)n_in; (void)out_size; (void)ws_size;
  const int*   target  = (const int*)  d_in[0];
  const float* context = (const float*)d_in[2];
  const float* table   = (const float*)d_in[3];
  const float* w_ih0   = (const float*)d_in[4];
  const float* w_hh0   = (const float*)d_in[5];
  const float* b_ih0   = (const float*)d_in[6];
  const float* b_hh0   = (const float*)d_in[7];
  const float* w_ih1   = (const float*)d_in[8];
  const float* w_hh1   = (const float*)d_in[9];
  const float* b_ih1   = (const float*)d_in[10];
  const float* b_hh1   = (const float*)d_in[11];
  const float* fc_w    = (const float*)d_in[12];
  const float* fc_b    = (const float*)d_in[13];
  float* out = (float*)d_out;

  uint8_t* ws = (uint8_t*)d_ws;
  size_t off = 0;
  auto alloc = [&](size_t bytes) {
    uint8_t* p = ws + off;
    off += (bytes + 255) & ~(size_t)255;
    return p;
  };
  unsigned*       bar   = (unsigned*)alloc(16384);
  unsigned short* XH    = (unsigned short*)alloc((size_t)4 * 32 * 2048 * 2);
  unsigned short* H0    = (unsigned short*)alloc((size_t)4 * 2 * 32 * 512 * 2);
  unsigned short* whh0b = (unsigned short*)alloc((size_t)1572864 * 2);
  unsigned short* w1cat = (unsigned short*)alloc((size_t)2 * 1536 * 1536 * 2);
  unsigned short* embb  = (unsigned short*)alloc((size_t)2097152 * 2);
  unsigned short* wih0b = (unsigned short*)alloc((size_t)1572864 * 2);
  unsigned short* gi0   = (unsigned short*)alloc((size_t)12582912 * 2);
  unsigned short* outsb = (unsigned short*)alloc((size_t)4194304 * 2);
  unsigned short* fcwb  = (unsigned short*)alloc((size_t)32768000 * 2);

  // partials + lse overlay gi0's region (dead after pers_kernel)
  float* pm     = (float*)gi0;
  float* ps     = pm + (size_t)4096 * 250;
  float* lsebuf = ps + (size_t)4096 * 250;

  // allow >64KB dynamic LDS for pers_kernel
  static bool attr_done = false;
  if (!attr_done) {
    hipFuncSetAttribute(reinterpret_cast<const void*>(pers_kernel),
                        hipFuncAttributeMaxDynamicSharedMemorySize, 98816);
    attr_done = true;
  }

  // prep
  zero_flags<<<dim3(1), 256, 0, stream>>>(bar);
  cast_bf16<<<dim3(1536), 256, 0, stream>>>(w_ih0, wih0b, 393216);
  cast_bf16<<<dim3(1536), 256, 0, stream>>>(w_hh0, whh0b, 393216);
  cast_bf16<<<dim3(32000), 256, 0, stream>>>(fc_w, fcwb, 8192000);
  pack_w1<<<dim3(3072), 256, 0, stream>>>(w_ih1, w_hh1, w1cat);
  embed_gather<<<dim3(4096), 128, 0, stream>>>(target, table, embb);

  // gi0 = emb * w_ih0^T + b_ih0  (bf16 out [d][4096][1536])
  gemm_nt<0><<<dim3(32, 12, 2), 256, 0, stream>>>(
      embb, wih0b, b_ih0, gi0, 512, 1536,
      (size_t)1536 * 512, (size_t)4096 * 1536, (size_t)1536, nullptr, nullptr);

  // recurrence: one persistent kernel, direct flag sync (no coordinator)
  pers_kernel<<<dim3(128), 384, 98816, stream>>>(
      gi0, whh0b, w1cat, b_hh0, b_ih1, b_hh1, context, XH, H0, outsb, bar);

  // logits = outs * fc_w^T + fc_b  (row remap (s,b)->(b,s)) + LSE partials
  gemm_nt<1><<<dim3(32, 250, 1), 256, 0, stream>>>(
      outsb, fcwb, fc_b, out, 1024, Vv, 0, 0, 0, pm, ps);

  // log_softmax: reduce partials then subtract
  lse_reduce<<<dim3(32), 128, 0, stream>>>(pm, ps, lsebuf);
  sub_lse<<<dim3(4096), 256, 0, stream>>>(out, lsebuf);
}